// Round 6
// baseline (398.311 us; speedup 1.0000x reference)
//
#include <hip/hip_runtime.h>
#include <math.h>

#define NR 10
#define CH 7
#define HID 128
#define NH 4
#define NL 3
#define TOK_FEATS (NR * HID)   // 1280
#define NTOK 16384
#define G 8                    // tokens per block (1 wave each)
#define MROWS (G * NR)         // 80 real A-rows = exactly 5 M-tiles
#define SNSTR 130              // padded fp32 row stride for s_nodes

// LDS layout (bytes): 80000 total -> 2 blocks/CU (16 waves/CU, 50% occ)
#define SN_OFF   0             // float [80][130]        = 41600  (nodes fp32, residual)
#define SA_OFF   41600         // f16   [80][128] swz    = 20480  (A: nodes-f16 / mix chunk)
#define ASD_OFF  62080         // float [80][8]          = 2560   (a_src|a_dst)
#define SAL_OFF  64640         // float [8][4][10][12]   = 15360  (alpha, 0.25-folded)
#define SMEM_BYTES 80000

typedef _Float16 f16;
typedef _Float16 half8 __attribute__((ext_vector_type(8)));
typedef float f32x4 __attribute__((ext_vector_type(4)));

__device__ __forceinline__ float gelu_exact(float x) {
    return 0.5f * x * (1.0f + erff(x * 0.70710678118654752f));
}
__device__ __forceinline__ float rlane(float v, int lane) {
    return __int_as_float(__builtin_amdgcn_readlane(__float_as_int(v), lane));
}
// frag read: 16B at (rc*256 + kByte), XOR-swizzled (G4: kills 256B-stride conflicts)
__device__ __forceinline__ half8 ldfrag(const char* base, int rc, int kByte) {
    return *(const half8*)(base + ((((rc) << 8) + (kByte)) ^ (((rc) & 7) << 4)));
}
// packed f16-pair write: lane owns cols (2*lane, 2*lane+1) of row -> one b32
__device__ __forceinline__ void stPair(char* sA, int row, int lane, float a, float b) {
    const unsigned short ha = __builtin_bit_cast(unsigned short, (f16)a);
    const unsigned short hb = __builtin_bit_cast(unsigned short, (f16)b);
    const unsigned u = ((unsigned)hb << 16) | ha;
    *(unsigned*)(sA + ((((row) << 8) + ((lane) << 2)) ^ (((row) & 7) << 4))) = u;
}
__device__ __forceinline__ half8 h8cast(uint4 u) { return __builtin_bit_cast(half8, u); }
__device__ __forceinline__ f32x4 mfma16(half8 a, half8 b, f32x4 c) {
    return __builtin_amdgcn_mfma_f32_16x16x32_f16(a, b, c, 0, 0, 0);
}

// adjacency bitmasks: bit j of adj[i] == edge j->i (incl self loops)
__device__ __constant__ unsigned short kAdj[NR] = {
    0x01F, 0x0A7, 0x08F, 0x00D, 0x031, 0x072, 0x260, 0x186, 0x180, 0x240
};
// compile-time copy: fully-unrolled sparse mix (36 edges, dead FMAs fold away)
constexpr unsigned kAdjC[NR] = {
    0x01F, 0x0A7, 0x08F, 0x00D, 0x031, 0x072, 0x260, 0x186, 0x180, 0x240
};

// ---------------- prep A: W_gat -> Wcat_T fp16 ([l][h][col e][k d]) ----------------
__global__ void prep_copy(const float* __restrict__ W_gat, f16* __restrict__ ws) {
    const int t = blockIdx.x * 256 + threadIdx.x;   // grid covers exactly NW
    const int kk = t & 127, col = (t >> 7) & 127, h = (t >> 14) & 3, l = t >> 16;
    ws[t] = (f16)W_gat[((l * HID + kk) * NH + h) * HID + col];
}

// ---------------- prep B: U = W @ att_{src,dst} fp16 ([l][c 16][d]; c<4 src,
// 4..7 dst, 8..15 zero). 48 blocks x 128 thr, float4 fully unrolled: the R5 prep
// did this with 24 waves of unroll-4 scalar strided loads -> ~100us latency-bound.
__global__ void prep_u(const float* __restrict__ W_gat,
                       const float* __restrict__ att_src,
                       const float* __restrict__ att_dst,
                       f16* __restrict__ ws) {
    const int NW = NL * NH * HID * HID;          // 196608
    const int c = blockIdx.x & 15, l = blockIdx.x >> 4, d = threadIdx.x;
    float v = 0.f;
    if (c < 8) {
        const int h = c & 3;
        const float* att = ((c < 4) ? att_src : att_dst) + (l * NH + h) * HID;
        const float4* wr = (const float4*)(W_gat + ((l * HID + d) * NH + h) * HID);
        #pragma unroll
        for (int e4 = 0; e4 < 32; ++e4) {
            const float4 wv = wr[e4];
            const float4 av = *(const float4*)(att + e4 * 4);
            v = fmaf(wv.x, av.x, v); v = fmaf(wv.y, av.y, v);
            v = fmaf(wv.z, av.z, v); v = fmaf(wv.w, av.w, v);
        }
    }
    ws[NW + (l * 16 + c) * HID + d] = (f16)v;
}

// ---------------- main kernel: 8 tokens/block, 8 waves, MFMA GAT ----------------
__global__ void
__attribute__((amdgpu_flat_work_group_size(512, 512), amdgpu_waves_per_eu(4, 4)))
brain_graph_kernel(const float* __restrict__ x,
                   const float* __restrict__ W_enc,
                   const float* __restrict__ b_enc,
                   const float* __restrict__ g_enc,
                   const float* __restrict__ beta_enc,
                   const float* __restrict__ b_gat,
                   const f16* __restrict__ wq,
                   float* __restrict__ out_gf,
                   float* __restrict__ out_enc) {
    extern __shared__ __align__(16) char smem[];
    float* sN   = (float*)(smem + SN_OFF);
    char*  sA   = smem + SA_OFF;
    float* sasd = (float*)(smem + ASD_OFF);
    float* sAL  = (float*)(smem + SAL_OFF);

    const int w     = threadIdx.x >> 6;   // wave = token slot (0..7)
    const int lane  = threadIdx.x & 63;
    const int token = blockIdx.x * G + w;
    const int rb    = w * NR;             // this wave's global A-row base
    const int cl    = lane & 15;          // frag row/col-low
    const int kg    = lane >> 4;          // frag k-group

    // ============ encoder: Linear(7->128) + LN + GELU (1 wave / token) ============
    const float xv0 = x[(size_t)token * (NR * CH) + lane];
    const float xv1 = (lane < NR * CH - 64) ? x[(size_t)token * (NR * CH) + 64 + lane] : 0.f;
    {
        const int d0 = lane, d1 = lane + 64;
        #pragma unroll
        for (int r = 0; r < NR; ++r) {
            float a0 = b_enc[r * HID + d0];
            float a1 = b_enc[r * HID + d1];
            #pragma unroll
            for (int c = 0; c < CH; ++c) {
                const int idx = r * CH + c;
                const float xs = (idx < 64) ? rlane(xv0, idx) : rlane(xv1, idx - 64);
                a0 = fmaf(xs, W_enc[idx * HID + d0], a0);
                a1 = fmaf(xs, W_enc[idx * HID + d1], a1);
            }
            float s = a0 + a1, sq = a0 * a0 + a1 * a1;
            #pragma unroll
            for (int off = 32; off > 0; off >>= 1) {
                s  += __shfl_xor(s, off);
                sq += __shfl_xor(sq, off);
            }
            const float mu = s * (1.0f / 128.0f);
            const float rstd = rsqrtf(sq * (1.0f / 128.0f) - mu * mu + 1e-5f);
            const float e0 = gelu_exact((a0 - mu) * rstd * g_enc[r * HID + d0] + beta_enc[r * HID + d0]);
            const float e1 = gelu_exact((a1 - mu) * rstd * g_enc[r * HID + d1] + beta_enc[r * HID + d1]);
            sN[(rb + r) * SNSTR + d0] = e0;
            sN[(rb + r) * SNSTR + d1] = e1;
            out_enc[(size_t)token * TOK_FEATS + r * HID + d0] = e0;
            out_enc[(size_t)token * TOK_FEATS + r * HID + d1] = e1;
        }
    }
    __syncthreads();

    const char* Wq = (const char*)wq;                                  // [l][h][e][d]
    const char* Uq = (const char*)(wq + NL * NH * HID * HID);          // U_T

    for (int l = 0; l < NL; ++l) {
        // ---- prefetch U frags for step 2 (consumed after step-1 barrier) ----
        uint4 u0, u1, u2, u3;
        if (w < 5) {
            const char* ub = Uq + (((l * 16 + cl) * 128 + kg * 8) << 1);
            u0 = *(const uint4*)(ub);
            u1 = *(const uint4*)(ub + 64);
            u2 = *(const uint4*)(ub + 128);
            u3 = *(const uint4*)(ub + 192);
        }

        // ---- step 1: nodes-f16 into sA (NO long-lived register cache: R5's
        // ndA/ndB[10] held across the layer was the arch-VGPR spill source) ----
        #pragma unroll
        for (int n = 0; n < NR; ++n) {
            const float2 v = *(const float2*)&sN[(rb + n) * SNSTR + 2 * lane];
            stPair(sA, rb + n, lane, v.x, v.y);
        }
        __syncthreads();

        // ---- step 2: a_sd MFMA (waves 0..4, mt=w), B = U_T from L2 ----
        if (w < 5) {
            const int row = w * 16 + cl;
            f32x4 cu = {0.f, 0.f, 0.f, 0.f};
            cu = mfma16(ldfrag(sA, row, 0 * 64 + kg * 16), h8cast(u0), cu);
            cu = mfma16(ldfrag(sA, row, 1 * 64 + kg * 16), h8cast(u1), cu);
            cu = mfma16(ldfrag(sA, row, 2 * 64 + kg * 16), h8cast(u2), cu);
            cu = mfma16(ldfrag(sA, row, 3 * 64 + kg * 16), h8cast(u3), cu);
            if (cl < 8) {
                #pragma unroll
                for (int r = 0; r < 4; ++r)
                    sasd[(w * 16 + kg * 4 + r) * 8 + cl] = cu[r];
            }
        }
        __syncthreads();

        // ---- step 3: masked leaky-relu softmax (lanes 0..39 of each wave) ----
        if (lane < NR * NH) {
            const int i = lane >> 2, h = lane & 3;
            const unsigned mask = kAdj[i];
            const float adv = sasd[(rb + i) * 8 + 4 + h];
            float lg[NR];
            float mx = -1e30f;
            #pragma unroll
            for (int j = 0; j < NR; ++j) {
                float v = adv + sasd[(rb + j) * 8 + h];
                v = (v > 0.f) ? v : 0.2f * v;
                v = ((mask >> j) & 1u) ? v : -1e9f;
                lg[j] = v;
                mx = fmaxf(mx, v);
            }
            float ssum = 0.f;
            #pragma unroll
            for (int j = 0; j < NR; ++j) {
                const float e = __expf(lg[j] - mx);
                lg[j] = e;
                ssum += e;
            }
            const float inv = 0.25f / ssum;   // fold mean-over-heads
            const int base = ((w * 4 + h) * 10 + i) * 12;
            #pragma unroll
            for (int j = 0; j < NR; ++j) sAL[base + j] = lg[j] * inv;
        }
        __syncthreads();

        // ---- step 4: 4 K-chunks: sparse mix_h -> sA ; pipelined B-frags from L2 ----
        f32x4 C[5] = {};
        #pragma unroll
        for (int h = 0; h < NH; ++h) {
            // issue first B-frag load now: its L2 latency hides under the mix FMAs
            const char* wb = Wq + ((size_t)((l * 4 + h) * 128 + w * 16 + cl) << 8) + kg * 16;
            uint4 bcur = *(const uint4*)(wb);
            // node values loaded fresh from LDS: live only inside this phase
            float2 nv[NR];
            #pragma unroll
            for (int n = 0; n < NR; ++n)
                nv[n] = *(const float2*)&sN[(rb + n) * SNSTR + 2 * lane];
            // mix[i, d] = sum_{j in N(i)} alpha[i,j,h]*nodes[j,d] (sparse, 36 edges;
            // alpha == 0 exactly for non-edges since exp(-1e9-mx) underflows)
            #pragma unroll
            for (int i = 0; i < NR; ++i) {
                const float4* ap = (const float4*)&sAL[((w * 4 + h) * 10 + i) * 12];
                const float4 A0 = ap[0], A1 = ap[1], A2 = ap[2];  // A2.z/.w unused
                const float al[NR] = {A0.x, A0.y, A0.z, A0.w, A1.x,
                                      A1.y, A1.z, A1.w, A2.x, A2.y};
                float m0 = 0.f, m1 = 0.f;
                #pragma unroll
                for (int j = 0; j < NR; ++j) {
                    if (kAdjC[i] & (1u << j)) {
                        m0 = fmaf(al[j], nv[j].x, m0);
                        m1 = fmaf(al[j], nv[j].y, m1);
                    }
                }
                stPair(sA, rb + i, lane, m0, m1);
            }
            __syncthreads();
            // MFMA over 4 K-frags, B pipelined one-ahead (8 live B regs, not 16)
            #pragma unroll
            for (int ks = 0; ks < 4; ++ks) {
                const half8 b = h8cast(bcur);
                if (ks < 3) bcur = *(const uint4*)(wb + (ks + 1) * 64);
                const int kB = ks * 64 + kg * 16;
                #pragma unroll
                for (int mt = 0; mt < 5; ++mt)
                    C[mt] = mfma16(ldfrag(sA, mt * 16 + cl, kB), b, C[mt]);
            }
            if (h < NH - 1) __syncthreads();   // protect sA before next mix overwrite
        }

        // ---- step 5: +bias, GELU, +residual -> sN only (no partial-line HBM) ----
        const float bg = b_gat[l * HID + w * 16 + cl];
        const int col = w * 16 + cl;
        #pragma unroll
        for (int mt = 0; mt < 5; ++mt) {
            #pragma unroll
            for (int r = 0; r < 4; ++r) {
                const int row = mt * 16 + kg * 4 + r;
                sN[row * SNSTR + col] = gelu_exact(C[mt][r] + bg) + sN[row * SNSTR + col];
            }
        }
        __syncthreads();   // sN complete; also fences sA reads vs next layer's writes
    }

    // ---- final out_gf store: per-token contiguous 256B bursts (full lines) ----
    #pragma unroll
    for (int r = 0; r < NR; ++r) {
        out_gf[(size_t)token * TOK_FEATS + r * HID + lane]      = sN[(rb + r) * SNSTR + lane];
        out_gf[(size_t)token * TOK_FEATS + r * HID + 64 + lane] = sN[(rb + r) * SNSTR + 64 + lane];
    }
}

extern "C" void kernel_launch(void* const* d_in, const int* in_sizes, int n_in,
                              void* d_out, int out_size, void* d_ws, size_t ws_size,
                              hipStream_t stream) {
    const float* x        = (const float*)d_in[0];
    const float* W_enc    = (const float*)d_in[1];
    const float* b_enc    = (const float*)d_in[2];
    const float* g_enc    = (const float*)d_in[3];
    const float* beta_enc = (const float*)d_in[4];
    const float* W_gat    = (const float*)d_in[5];
    const float* att_src  = (const float*)d_in[6];
    const float* att_dst  = (const float*)d_in[7];
    const float* b_gat    = (const float*)d_in[8];

    float* out_gf  = (float*)d_out;
    float* out_enc = (float*)d_out + (size_t)NTOK * TOK_FEATS;
    f16* wsw = (f16*)d_ws;   // 405504 B used

    static bool attr_done = false;
    if (!attr_done) {
        (void)hipFuncSetAttribute((const void*)brain_graph_kernel,
                                  hipFuncAttributeMaxDynamicSharedMemorySize, SMEM_BYTES);
        attr_done = true;
    }

    prep_copy<<<NL * NH * HID * HID / 256, 256, 0, stream>>>(W_gat, wsw);
    prep_u<<<NL * 16, 128, 0, stream>>>(W_gat, att_src, att_dst, wsw);

    brain_graph_kernel<<<NTOK / G, 512, SMEM_BYTES, stream>>>(
        x, W_enc, b_enc, g_enc, beta_enc, b_gat, wsw, out_gf, out_enc);
}